// Round 1
// baseline (163.277 us; speedup 1.0000x reference)
//
#include <hip/hip_runtime.h>
#include <math.h>

#define N_PTS 65536
#define BATCH 8
#define KCL   64
#define CHUNK 1024
#define THREADS 256

// ---- ordered-uint <-> float for atomicMax on floats (finite values) ----
__device__ __forceinline__ unsigned f2o(float f) {
    unsigned u = __float_as_uint(f);
    return (u & 0x80000000u) ? ~u : (u | 0x80000000u);
}
__device__ __forceinline__ float o2f(unsigned k) {
    return (k & 0x80000000u) ? __uint_as_float(k ^ 0x80000000u) : __uint_as_float(~k);
}

// K1: per-(set,b,k) max of logit = x_n . w_k over a CHUNK of points, atomicMax-merged.
__global__ __launch_bounds__(THREADS) void k_max(const float* __restrict__ tmpl,
                                                 const float* __restrict__ srcf,
                                                 const float* __restrict__ Wmat,
                                                 unsigned* __restrict__ maxkey) {
    const int chunk = blockIdx.x;   // N_PTS/CHUNK
    const int b     = blockIdx.y;   // BATCH
    const int set   = blockIdx.z;   // 0=template, 1=source
    const float* feat = set ? srcf : tmpl;
    const int n0 = chunk * CHUNK;

    __shared__ float xs[3][CHUNK];
    __shared__ float red[4][KCL];

    const int tid = threadIdx.x;
    const float* base = feat + (size_t)b * 3 * N_PTS + n0;
    // stage CHUNK points (3 planes) via float4
    for (int i = tid; i < 3 * (CHUNK / 4); i += THREADS) {
        int d = i / (CHUNK / 4);
        int p = i % (CHUNK / 4);
        float4 v = ((const float4*)(base + (size_t)d * N_PTS))[p];
        ((float4*)&xs[d][0])[p] = v;
    }
    __syncthreads();

    const int lane = tid & 63;   // lane <-> cluster k
    const int wv   = tid >> 6;
    const float w0 = Wmat[lane];
    const float w1 = Wmat[KCL + lane];
    const float w2 = Wmat[2 * KCL + lane];

    float m = -3.402823466e38f;
    const int p0 = wv * (CHUNK / 4);
    for (int p = p0; p < p0 + CHUNK / 4; ++p) {
        float l = fmaf(xs[0][p], w0, fmaf(xs[1][p], w1, xs[2][p] * w2));
        m = fmaxf(m, l);
    }
    red[wv][lane] = m;
    __syncthreads();
    if (tid < KCL) {
        float mm = fmaxf(fmaxf(red[0][tid], red[1][tid]),
                         fmaxf(red[2][tid], red[3][tid]));
        atomicMax(&maxkey[((size_t)set * BATCH + b) * KCL + tid], f2o(mm));
    }
}

// K2: Z = sum exp(l-m), S_d = sum exp(l-m)*x_d per (set,b,k)
__global__ __launch_bounds__(THREADS) void k_sum(const float* __restrict__ tmpl,
                                                 const float* __restrict__ srcf,
                                                 const float* __restrict__ Wmat,
                                                 const unsigned* __restrict__ maxkey,
                                                 float* __restrict__ Zs,
                                                 float* __restrict__ Ss) {
    const int chunk = blockIdx.x;
    const int b     = blockIdx.y;
    const int set   = blockIdx.z;
    const float* feat = set ? srcf : tmpl;
    const int n0 = chunk * CHUNK;

    __shared__ float xs[3][CHUNK];
    __shared__ float red[4][KCL][4];

    const int tid = threadIdx.x;
    const float* base = feat + (size_t)b * 3 * N_PTS + n0;
    for (int i = tid; i < 3 * (CHUNK / 4); i += THREADS) {
        int d = i / (CHUNK / 4);
        int p = i % (CHUNK / 4);
        float4 v = ((const float4*)(base + (size_t)d * N_PTS))[p];
        ((float4*)&xs[d][0])[p] = v;
    }
    __syncthreads();

    const int lane = tid & 63;
    const int wv   = tid >> 6;
    const float w0 = Wmat[lane];
    const float w1 = Wmat[KCL + lane];
    const float w2 = Wmat[2 * KCL + lane];
    const int sb = ((int)set * BATCH + b) * KCL + lane;
    const float m = o2f(maxkey[sb]);

    float z = 0.f, s0 = 0.f, s1 = 0.f, s2 = 0.f;
    const int p0 = wv * (CHUNK / 4);
    for (int p = p0; p < p0 + CHUNK / 4; ++p) {
        float x0 = xs[0][p], x1 = xs[1][p], x2 = xs[2][p];
        float l = fmaf(x0, w0, fmaf(x1, w1, x2 * w2));
        float e = __expf(l - m);
        z += e;
        s0 = fmaf(e, x0, s0);
        s1 = fmaf(e, x1, s1);
        s2 = fmaf(e, x2, s2);
    }
    red[wv][lane][0] = z;
    red[wv][lane][1] = s0;
    red[wv][lane][2] = s1;
    red[wv][lane][3] = s2;
    __syncthreads();
    if (tid < KCL) {
        float rz  = red[0][tid][0] + red[1][tid][0] + red[2][tid][0] + red[3][tid][0];
        float rs0 = red[0][tid][1] + red[1][tid][1] + red[2][tid][1] + red[3][tid][1];
        float rs1 = red[0][tid][2] + red[1][tid][2] + red[2][tid][2] + red[3][tid][2];
        float rs2 = red[0][tid][3] + red[1][tid][3] + red[2][tid][3] + red[3][tid][3];
        int idx = ((int)set * BATCH + b) * KCL + tid;
        atomicAdd(&Zs[idx], rz);
        atomicAdd(&Ss[idx * 3 + 0], rs0);
        atomicAdd(&Ss[idx * 3 + 1], rs1);
        atomicAdd(&Ss[idx * 3 + 2], rs2);
    }
}

// K3: per-batch transform solve (fp64): centroids, Wm, polar factor via Jacobi, det flip, T.
__global__ void k_transform(const float* __restrict__ Zs,
                            const float* __restrict__ Ss,
                            float* __restrict__ RT) {  // [BATCH][12]: R row-major + T
    const int b = threadIdx.x;
    if (b >= BATCH) return;

    const double inv_npi = 1.0 / (1.0 + 2e-8);           // gamma/(Npi+eps), Npi = 1+eps
    const double pi_c = (1.0 + 1e-8) / (double)N_PTS;    // pi[b,k] is constant

    // pass 1: centroid sums (x = source, y = template)
    double st[3] = {0, 0, 0}, ss[3] = {0, 0, 0};
    for (int k = 0; k < KCL; ++k) {
        int it = (0 * BATCH + b) * KCL + k;
        int is = (1 * BATCH + b) * KCL + k;
        double zt = (double)Zs[it], zs = (double)Zs[is];
        for (int d = 0; d < 3; ++d) {
            st[d] += (double)Ss[it * 3 + d] / zt;
            ss[d] += (double)Ss[is * 3 + d] / zs;
        }
    }
    double cy[3], cx[3];
    for (int d = 0; d < 3; ++d) {
        cy[d] = pi_c * inv_npi * st[d];
        cx[d] = pi_c * inv_npi * ss[d];
    }

    // pass 2: Wm[d][e] = pi * sum_k (mu_t-cy)_d (mu_s-cx)_e
    double A[3][3] = {{0,0,0},{0,0,0},{0,0,0}};
    for (int k = 0; k < KCL; ++k) {
        int it = (0 * BATCH + b) * KCL + k;
        int is = (1 * BATCH + b) * KCL + k;
        double zt = (double)Zs[it], zs = (double)Zs[is];
        double mt[3], ms[3];
        for (int d = 0; d < 3; ++d) {
            mt[d] = inv_npi * (double)Ss[it * 3 + d] / zt - cy[d];
            ms[d] = inv_npi * (double)Ss[is * 3 + d] / zs - cx[d];
        }
        for (int d = 0; d < 3; ++d)
            for (int e = 0; e < 3; ++e)
                A[d][e] += mt[d] * ms[e];
    }
    for (int d = 0; d < 3; ++d)
        for (int e = 0; e < 3; ++e)
            A[d][e] *= pi_c;

    // G = A^T A
    double G[3][3];
    for (int i = 0; i < 3; ++i)
        for (int j = 0; j < 3; ++j) {
            double acc = 0;
            for (int d = 0; d < 3; ++d) acc += A[d][i] * A[d][j];
            G[i][j] = acc;
        }

    // Jacobi eigendecomposition of G (columns of V = eigenvectors)
    double V[3][3] = {{1,0,0},{0,1,0},{0,0,1}};
    const int pairs[3][2] = {{0,1},{0,2},{1,2}};
    for (int sweep = 0; sweep < 30; ++sweep) {
        double off = fabs(G[0][1]) + fabs(G[0][2]) + fabs(G[1][2]);
        if (off < 1e-300) break;
        for (int pi_i = 0; pi_i < 3; ++pi_i) {
            int p = pairs[pi_i][0], q = pairs[pi_i][1];
            double apq = G[p][q];
            if (fabs(apq) < 1e-300) continue;
            double tau = (G[q][q] - G[p][p]) / (2.0 * apq);
            double t = (tau >= 0 ? 1.0 : -1.0) / (fabs(tau) + sqrt(1.0 + tau * tau));
            double c = 1.0 / sqrt(1.0 + t * t);
            double s = t * c;
            double gpp = G[p][p], gqq = G[q][q];
            G[p][p] = gpp - t * apq;
            G[q][q] = gqq + t * apq;
            G[p][q] = G[q][p] = 0.0;
            int r = 3 - p - q;
            double grp = G[r][p], grq = G[r][q];
            G[r][p] = G[p][r] = c * grp - s * grq;
            G[r][q] = G[q][r] = s * grp + c * grq;
            for (int rr = 0; rr < 3; ++rr) {
                double vrp = V[rr][p], vrq = V[rr][q];
                V[rr][p] = c * vrp - s * vrq;
                V[rr][q] = s * vrp + c * vrq;
            }
        }
    }

    // M = V diag(1/sqrt(lam)) V^T ; R0 = A * M  (polar factor = U @ Vh)
    double invs[3];
    for (int i = 0; i < 3; ++i) {
        double lam = G[i][i];
        invs[i] = 1.0 / sqrt(lam > 1e-300 ? lam : 1e-300);
    }
    double M[3][3];
    for (int i = 0; i < 3; ++i)
        for (int j = 0; j < 3; ++j) {
            double acc = 0;
            for (int m2 = 0; m2 < 3; ++m2) acc += V[i][m2] * V[j][m2] * invs[m2];
            M[i][j] = acc;
        }
    double R0[3][3];
    for (int d = 0; d < 3; ++d)
        for (int e = 0; e < 3; ++e) {
            double acc = 0;
            for (int m2 = 0; m2 < 3; ++m2) acc += A[d][m2] * M[m2][e];
            R0[d][e] = acc;
        }

    // reference: Vh[:,:,-1] *= sign(det(U@Vh)); R = U@Vh'  == flip 3rd column of R0
    double det = R0[0][0] * (R0[1][1] * R0[2][2] - R0[1][2] * R0[2][1])
               - R0[0][1] * (R0[1][0] * R0[2][2] - R0[1][2] * R0[2][0])
               + R0[0][2] * (R0[1][0] * R0[2][1] - R0[1][1] * R0[2][0]);
    double sg = (det >= 0.0) ? 1.0 : -1.0;
    R0[0][2] *= sg; R0[1][2] *= sg; R0[2][2] *= sg;

    double T[3];
    for (int d = 0; d < 3; ++d)
        T[d] = cy[d] - (R0[d][0] * cx[0] + R0[d][1] * cx[1] + R0[d][2] * cx[2]);

    float* rt = RT + b * 12;
    rt[0] = (float)R0[0][0]; rt[1] = (float)R0[0][1]; rt[2] = (float)R0[0][2];
    rt[3] = (float)R0[1][0]; rt[4] = (float)R0[1][1]; rt[5] = (float)R0[1][2];
    rt[6] = (float)R0[2][0]; rt[7] = (float)R0[2][1]; rt[8] = (float)R0[2][2];
    rt[9] = (float)T[0]; rt[10] = (float)T[1]; rt[11] = (float)T[2];
}

// K4: out[b,n,:] = R * x + T  (output layout (B,N,D) row-major)
__global__ __launch_bounds__(256) void k_apply(const float* __restrict__ srcf,
                                               const float* __restrict__ RT,
                                               float* __restrict__ out) {
    const int idx = blockIdx.x * 256 + threadIdx.x;  // 0 .. B*N-1
    const int b = idx >> 16;
    const int n = idx & (N_PTS - 1);
    const float* rt = RT + b * 12;
    const float* base = srcf + (size_t)b * 3 * N_PTS;
    float x0 = base[n];
    float x1 = base[N_PTS + n];
    float x2 = base[2 * N_PTS + n];
    float y0 = fmaf(rt[0], x0, fmaf(rt[1], x1, fmaf(rt[2], x2, rt[9])));
    float y1 = fmaf(rt[3], x0, fmaf(rt[4], x1, fmaf(rt[5], x2, rt[10])));
    float y2 = fmaf(rt[6], x0, fmaf(rt[7], x1, fmaf(rt[8], x2, rt[11])));
    size_t o = (size_t)idx * 3;
    out[o + 0] = y0;
    out[o + 1] = y1;
    out[o + 2] = y2;
}

extern "C" void kernel_launch(void* const* d_in, const int* in_sizes, int n_in,
                              void* d_out, int out_size, void* d_ws, size_t ws_size,
                              hipStream_t stream) {
    const float* tmpl = (const float*)d_in[0];   // (B,3,N) f32
    const float* srcf = (const float*)d_in[1];   // (B,3,N) f32
    const float* Wmat = (const float*)d_in[2];   // (3,K) f32
    float* out = (float*)d_out;                  // (B,N,3) f32

    // workspace layout (floats): [0,1024) maxkey(u32) | [1024,2048) Z | [2048,5120) S | [5120,5216) RT
    unsigned* maxkey = (unsigned*)d_ws;
    float* Zs = (float*)d_ws + 1024;
    float* Ss = (float*)d_ws + 2048;
    float* RT = (float*)d_ws + 5120;

    hipMemsetAsync(d_ws, 0, 5120 * sizeof(float), stream);

    dim3 grid1(N_PTS / CHUNK, BATCH, 2);
    k_max<<<grid1, THREADS, 0, stream>>>(tmpl, srcf, Wmat, maxkey);
    k_sum<<<grid1, THREADS, 0, stream>>>(tmpl, srcf, Wmat, maxkey, Zs, Ss);
    k_transform<<<1, 64, 0, stream>>>(Zs, Ss, RT);
    k_apply<<<(BATCH * N_PTS) / 256, 256, 0, stream>>>(srcf, RT, out);
}

// Round 3
// 111.757 us; speedup vs baseline: 1.4610x; 1.4610x over previous
//
#include <hip/hip_runtime.h>

#define N_PTS 65536
#define BATCH 8
#define KCL   64
#define CHUNK 1024
#define THREADS 256
#define LOG2E 1.44269504088896340736f

// fp64 reciprocal without v_div_*_f64: float rcp seed + 2 Newton iterations
// (err ~6e-8 -> ~4e-15 -> < double eps). ~15 cyc vs ~100+ for a real fp64 div.
__device__ __forceinline__ double drcp(double x) {
    double r = (double)(1.0f / (float)x);
    r = r * (2.0 - x * r);
    r = r * (2.0 - x * r);
    return r;
}

// hardware 2^x (v_exp_f32) — avoid __exp2f name (collides with glibc math.h macros)
__device__ __forceinline__ float hw_exp2(float x) {
    return __builtin_amdgcn_exp2f(x);
}

// K1: single data pass. Per (chunk,b,set) block: stage 1024 points in LDS,
// lane<->cluster k, accumulate Z = sum 2^(l*log2e) = sum e^l and S_d = sum e^l x_d.
// No max subtraction: logits are bounded (|x.w| <~ 30, e^30*65536 ~ 7e17 << fp32 max)
// and softmax is shift-invariant, so shift 0 is numerically safe here.
__global__ __launch_bounds__(THREADS) void k_sum(const float* __restrict__ tmpl,
                                                 const float* __restrict__ srcf,
                                                 const float* __restrict__ Wmat,
                                                 float* __restrict__ Zs,
                                                 float* __restrict__ Ss) {
    const int chunk = blockIdx.x;
    const int b     = blockIdx.y;
    const int set   = blockIdx.z;
    const float* feat = set ? srcf : tmpl;
    const int n0 = chunk * CHUNK;

    __shared__ float xs[3][CHUNK];
    __shared__ float red[4][KCL][4];

    const int tid = threadIdx.x;
    const float* base = feat + (size_t)b * 3 * N_PTS + n0;
    for (int i = tid; i < 3 * (CHUNK / 4); i += THREADS) {
        int d = i / (CHUNK / 4);
        int p = i % (CHUNK / 4);
        float4 v = ((const float4*)(base + (size_t)d * N_PTS))[p];
        ((float4*)&xs[d][0])[p] = v;
    }
    __syncthreads();

    const int lane = tid & 63;   // lane <-> cluster k
    const int wv   = tid >> 6;
    // fold log2e into w so exp is a single v_exp_f32 (2^x)
    const float w0 = Wmat[lane] * LOG2E;
    const float w1 = Wmat[KCL + lane] * LOG2E;
    const float w2 = Wmat[2 * KCL + lane] * LOG2E;

    float z = 0.f, s0 = 0.f, s1 = 0.f, s2 = 0.f;
    const int q0 = wv * (CHUNK / 16);   // 64 float4-groups per wv
    for (int q = q0; q < q0 + CHUNK / 16; ++q) {
        float4 a = ((const float4*)&xs[0][0])[q];   // broadcast ds_read_b128
        float4 c = ((const float4*)&xs[1][0])[q];
        float4 d = ((const float4*)&xs[2][0])[q];
        {
            float l = fmaf(a.x, w0, fmaf(c.x, w1, d.x * w2));
            float e = hw_exp2(l);
            z += e; s0 = fmaf(e, a.x, s0); s1 = fmaf(e, c.x, s1); s2 = fmaf(e, d.x, s2);
        }
        {
            float l = fmaf(a.y, w0, fmaf(c.y, w1, d.y * w2));
            float e = hw_exp2(l);
            z += e; s0 = fmaf(e, a.y, s0); s1 = fmaf(e, c.y, s1); s2 = fmaf(e, d.y, s2);
        }
        {
            float l = fmaf(a.z, w0, fmaf(c.z, w1, d.z * w2));
            float e = hw_exp2(l);
            z += e; s0 = fmaf(e, a.z, s0); s1 = fmaf(e, c.z, s1); s2 = fmaf(e, d.z, s2);
        }
        {
            float l = fmaf(a.w, w0, fmaf(c.w, w1, d.w * w2));
            float e = hw_exp2(l);
            z += e; s0 = fmaf(e, a.w, s0); s1 = fmaf(e, c.w, s1); s2 = fmaf(e, d.w, s2);
        }
    }
    red[wv][lane][0] = z;
    red[wv][lane][1] = s0;
    red[wv][lane][2] = s1;
    red[wv][lane][3] = s2;
    __syncthreads();
    if (tid < KCL) {
        float rz  = red[0][tid][0] + red[1][tid][0] + red[2][tid][0] + red[3][tid][0];
        float rs0 = red[0][tid][1] + red[1][tid][1] + red[2][tid][1] + red[3][tid][1];
        float rs1 = red[0][tid][2] + red[1][tid][2] + red[2][tid][2] + red[3][tid][2];
        float rs2 = red[0][tid][3] + red[1][tid][3] + red[2][tid][3] + red[3][tid][3];
        int idx = ((int)set * BATCH + b) * KCL + tid;
        atomicAdd(&Zs[idx], rz);
        atomicAdd(&Ss[idx * 3 + 0], rs0);
        atomicAdd(&Ss[idx * 3 + 1], rs1);
        atomicAdd(&Ss[idx * 3 + 2], rs2);
    }
}

// K2: per-batch transform solve (fp64). Single pass over k using
// sum_k (mt-cy)(ms-cx)^T = P - (2 pi_c - 64 pi_c^2) Mt Ms^T; all reciprocals
// via drcp, Jacobi capped at 10 sweeps with relative tolerance.
__global__ void k_transform(const float* __restrict__ Zs,
                            const float* __restrict__ Ss,
                            float* __restrict__ RT) {  // [BATCH][12]: R row-major + T
    const int b = threadIdx.x;
    if (b >= BATCH) return;

    const double inv_npi = 1.0 / (1.0 + 2e-8);           // gamma/(Npi+eps), Npi = 1+eps
    const double pi_c = (1.0 + 1e-8) / (double)N_PTS;    // pi[b,k] is constant

    double Mt[3] = {0, 0, 0}, Ms[3] = {0, 0, 0};
    double P[3][3] = {{0,0,0},{0,0,0},{0,0,0}};
    for (int k = 0; k < KCL; ++k) {
        int it = (0 * BATCH + b) * KCL + k;
        int is = (1 * BATCH + b) * KCL + k;
        double izt = inv_npi * drcp((double)Zs[it]);
        double izs = inv_npi * drcp((double)Zs[is]);
        double mt[3], ms[3];
        for (int d = 0; d < 3; ++d) {
            mt[d] = (double)Ss[it * 3 + d] * izt;
            ms[d] = (double)Ss[is * 3 + d] * izs;
            Mt[d] += mt[d];
            Ms[d] += ms[d];
        }
        for (int d = 0; d < 3; ++d)
            for (int e = 0; e < 3; ++e)
                P[d][e] += mt[d] * ms[e];
    }
    double cy[3], cx[3];
    for (int d = 0; d < 3; ++d) { cy[d] = pi_c * Mt[d]; cx[d] = pi_c * Ms[d]; }

    const double coef = 2.0 * pi_c - 64.0 * pi_c * pi_c;
    double A[3][3];
    for (int d = 0; d < 3; ++d)
        for (int e = 0; e < 3; ++e)
            A[d][e] = pi_c * (P[d][e] - coef * Mt[d] * Ms[e]);

    // G = A^T A
    double G[3][3];
    for (int i = 0; i < 3; ++i)
        for (int j = 0; j < 3; ++j) {
            double acc = 0;
            for (int d = 0; d < 3; ++d) acc += A[d][i] * A[d][j];
            G[i][j] = acc;
        }

    // Jacobi eigendecomposition of G (columns of V = eigenvectors)
    double V[3][3] = {{1,0,0},{0,1,0},{0,0,1}};
    const int pairs[3][2] = {{0,1},{0,2},{1,2}};
    const double scale0 = fabs(G[0][0]) + fabs(G[1][1]) + fabs(G[2][2]) + 1e-300;
    for (int sweep = 0; sweep < 10; ++sweep) {
        double off = fabs(G[0][1]) + fabs(G[0][2]) + fabs(G[1][2]);
        if (off < 1e-28 * scale0) break;
        for (int pi_i = 0; pi_i < 3; ++pi_i) {
            int p = pairs[pi_i][0], q = pairs[pi_i][1];
            double apq = G[p][q];
            if (fabs(apq) < 1e-30 * scale0) continue;
            double tau = (G[q][q] - G[p][p]) * drcp(2.0 * apq);
            double t = ((tau >= 0) ? 1.0 : -1.0) * drcp(fabs(tau) + sqrt(1.0 + tau * tau));
            double c = drcp(sqrt(1.0 + t * t));
            double s = t * c;
            double gpp = G[p][p], gqq = G[q][q];
            G[p][p] = gpp - t * apq;
            G[q][q] = gqq + t * apq;
            G[p][q] = G[q][p] = 0.0;
            int r = 3 - p - q;
            double grp = G[r][p], grq = G[r][q];
            G[r][p] = G[p][r] = c * grp - s * grq;
            G[r][q] = G[q][r] = s * grp + c * grq;
            for (int rr = 0; rr < 3; ++rr) {
                double vrp = V[rr][p], vrq = V[rr][q];
                V[rr][p] = c * vrp - s * vrq;
                V[rr][q] = s * vrp + c * vrq;
            }
        }
    }

    // M = V diag(1/sqrt(lam)) V^T ; R0 = A * M  (polar factor = U @ Vh)
    double invs[3];
    for (int i = 0; i < 3; ++i) {
        double lam = G[i][i];
        invs[i] = drcp(sqrt(lam > 1e-300 ? lam : 1e-300));
    }
    double M[3][3];
    for (int i = 0; i < 3; ++i)
        for (int j = 0; j < 3; ++j) {
            double acc = 0;
            for (int m2 = 0; m2 < 3; ++m2) acc += V[i][m2] * V[j][m2] * invs[m2];
            M[i][j] = acc;
        }
    double R0[3][3];
    for (int d = 0; d < 3; ++d)
        for (int e = 0; e < 3; ++e) {
            double acc = 0;
            for (int m2 = 0; m2 < 3; ++m2) acc += A[d][m2] * M[m2][e];
            R0[d][e] = acc;
        }

    // reference: Vh[:,:,-1] *= sign(det(U@Vh)); R = U@Vh'  == flip 3rd column of R0
    double det = R0[0][0] * (R0[1][1] * R0[2][2] - R0[1][2] * R0[2][1])
               - R0[0][1] * (R0[1][0] * R0[2][2] - R0[1][2] * R0[2][0])
               + R0[0][2] * (R0[1][0] * R0[2][1] - R0[1][1] * R0[2][0]);
    double sg = (det >= 0.0) ? 1.0 : -1.0;
    R0[0][2] *= sg; R0[1][2] *= sg; R0[2][2] *= sg;

    double T[3];
    for (int d = 0; d < 3; ++d)
        T[d] = cy[d] - (R0[d][0] * cx[0] + R0[d][1] * cx[1] + R0[d][2] * cx[2]);

    float* rt = RT + b * 12;
    rt[0] = (float)R0[0][0]; rt[1] = (float)R0[0][1]; rt[2] = (float)R0[0][2];
    rt[3] = (float)R0[1][0]; rt[4] = (float)R0[1][1]; rt[5] = (float)R0[1][2];
    rt[6] = (float)R0[2][0]; rt[7] = (float)R0[2][1]; rt[8] = (float)R0[2][2];
    rt[9] = (float)T[0]; rt[10] = (float)T[1]; rt[11] = (float)T[2];
}

// K3: out[b,n,:] = R * x + T  (output layout (B,N,D) row-major)
__global__ __launch_bounds__(256) void k_apply(const float* __restrict__ srcf,
                                               const float* __restrict__ RT,
                                               float* __restrict__ out) {
    const int idx = blockIdx.x * 256 + threadIdx.x;  // 0 .. B*N-1
    const int b = idx >> 16;
    const int n = idx & (N_PTS - 1);
    const float* rt = RT + b * 12;
    const float* base = srcf + (size_t)b * 3 * N_PTS;
    float x0 = base[n];
    float x1 = base[N_PTS + n];
    float x2 = base[2 * N_PTS + n];
    float y0 = fmaf(rt[0], x0, fmaf(rt[1], x1, fmaf(rt[2], x2, rt[9])));
    float y1 = fmaf(rt[3], x0, fmaf(rt[4], x1, fmaf(rt[5], x2, rt[10])));
    float y2 = fmaf(rt[6], x0, fmaf(rt[7], x1, fmaf(rt[8], x2, rt[11])));
    size_t o = (size_t)idx * 3;
    out[o + 0] = y0;
    out[o + 1] = y1;
    out[o + 2] = y2;
}

extern "C" void kernel_launch(void* const* d_in, const int* in_sizes, int n_in,
                              void* d_out, int out_size, void* d_ws, size_t ws_size,
                              hipStream_t stream) {
    const float* tmpl = (const float*)d_in[0];   // (B,3,N) f32
    const float* srcf = (const float*)d_in[1];   // (B,3,N) f32
    const float* Wmat = (const float*)d_in[2];   // (3,K) f32
    float* out = (float*)d_out;                  // (B,N,3) f32

    // workspace (floats): [0,1024) Z | [1024,4096) S | [4096,4192) RT
    float* Zs = (float*)d_ws;
    float* Ss = (float*)d_ws + 1024;
    float* RT = (float*)d_ws + 4096;

    (void)hipMemsetAsync(d_ws, 0, 4096 * sizeof(float), stream);

    dim3 grid1(N_PTS / CHUNK, BATCH, 2);
    k_sum<<<grid1, THREADS, 0, stream>>>(tmpl, srcf, Wmat, Zs, Ss);
    k_transform<<<1, 64, 0, stream>>>(Zs, Ss, RT);
    k_apply<<<(BATCH * N_PTS) / 256, 256, 0, stream>>>(srcf, RT, out);
}

// Round 4
// 100.699 us; speedup vs baseline: 1.6214x; 1.1098x over previous
//
#include <hip/hip_runtime.h>

#define N_PTS 65536
#define BATCH 8
#define KCL   64
#define LOG2E 1.44269504088896340736f

// fp64 reciprocal: float rcp seed + 2 Newton iterations (quadratic: ~1e-7 -> 1e-14 -> <eps)
__device__ __forceinline__ double drcp(double x) {
    double r = (double)(1.0f / (float)x);
    r = r * (2.0 - x * r);
    r = r * (2.0 - x * r);
    return r;
}

__device__ __forceinline__ float hw_exp2(float x) {
    return __builtin_amdgcn_exp2f(x);
}

// K1: softmax-weighted sums. 512 blocks x 256 thr = 2048 waves; each wave owns a
// 512-point chunk of one (set,b); lane = cluster k (so per-lane accumulators ARE
// per-cluster -- no cross-lane reduction). Point coords are wave-uniform: pointer
// built from readfirstlane(wave id) so uniform float4 loads select s_load_dwordx4
// (scalar pipe), leaving VALU slots entirely for the 8-op/point inner loop.
// No max subtraction: logits bounded (|x.w| <~ 30; e^30*65536 ~ 7e17 << fp32 max).
__global__ __launch_bounds__(256) void k_sum(const float* __restrict__ tmpl,
                                             const float* __restrict__ srcf,
                                             const float* __restrict__ Wmat,
                                             float* __restrict__ Zs,
                                             float* __restrict__ Ss) {
    const int tid  = threadIdx.x;
    const int lane = tid & 63;
    const int wv   = tid >> 6;

    // wave-uniform scalar index (forces SGPR address chain)
    const int gw  = __builtin_amdgcn_readfirstlane(blockIdx.x * 4 + wv); // 0..2047
    const int set = gw >> 10;          // 1024 waves per set
    const int b   = (gw >> 7) & 7;     // 128 waves per (set,b)
    const int n0  = (gw & 127) * 512;  // 512-point chunk
    const float* bp = (set ? srcf : tmpl) + (size_t)b * 3 * N_PTS + n0;

    // per-lane cluster weights, log2e folded so exp is one v_exp_f32
    const float w0 = Wmat[lane] * LOG2E;
    const float w1 = Wmat[KCL + lane] * LOG2E;
    const float w2 = Wmat[2 * KCL + lane] * LOG2E;

    float z = 0.f, s0 = 0.f, s1 = 0.f, s2 = 0.f;
    const float4* p0 = (const float4*)bp;
    const float4* p1 = (const float4*)(bp + N_PTS);
    const float4* p2 = (const float4*)(bp + 2 * N_PTS);
#pragma unroll 4
    for (int q = 0; q < 128; ++q) {   // 128 float4-groups = 512 points
        float4 a = p0[q];   // uniform address -> s_load_dwordx4
        float4 c = p1[q];
        float4 d = p2[q];
        {
            float l = fmaf(a.x, w0, fmaf(c.x, w1, d.x * w2));
            float e = hw_exp2(l);
            z += e; s0 = fmaf(e, a.x, s0); s1 = fmaf(e, c.x, s1); s2 = fmaf(e, d.x, s2);
        }
        {
            float l = fmaf(a.y, w0, fmaf(c.y, w1, d.y * w2));
            float e = hw_exp2(l);
            z += e; s0 = fmaf(e, a.y, s0); s1 = fmaf(e, c.y, s1); s2 = fmaf(e, d.y, s2);
        }
        {
            float l = fmaf(a.z, w0, fmaf(c.z, w1, d.z * w2));
            float e = hw_exp2(l);
            z += e; s0 = fmaf(e, a.z, s0); s1 = fmaf(e, c.z, s1); s2 = fmaf(e, d.z, s2);
        }
        {
            float l = fmaf(a.w, w0, fmaf(c.w, w1, d.w * w2));
            float e = hw_exp2(l);
            z += e; s0 = fmaf(e, a.w, s0); s1 = fmaf(e, c.w, s1); s2 = fmaf(e, d.w, s2);
        }
    }

    // all 4 waves of a block share (set,b): merge in LDS, one atomic set per block
    __shared__ float red[4][KCL][4];
    red[wv][lane][0] = z;
    red[wv][lane][1] = s0;
    red[wv][lane][2] = s1;
    red[wv][lane][3] = s2;
    __syncthreads();
    if (tid < KCL) {
        float rz  = red[0][tid][0] + red[1][tid][0] + red[2][tid][0] + red[3][tid][0];
        float rs0 = red[0][tid][1] + red[1][tid][1] + red[2][tid][1] + red[3][tid][1];
        float rs1 = red[0][tid][2] + red[1][tid][2] + red[2][tid][2] + red[3][tid][2];
        float rs2 = red[0][tid][3] + red[1][tid][3] + red[2][tid][3] + red[3][tid][3];
        int idx = (set * BATCH + b) * KCL + tid;
        atomicAdd(&Zs[idx], rz);
        atomicAdd(&Ss[idx * 3 + 0], rs0);
        atomicAdd(&Ss[idx * 3 + 1], rs1);
        atomicAdd(&Ss[idx * 3 + 2], rs2);
    }
}

// K2 (fused): every block redundantly solves the 8 per-batch transforms into LDS
// (wave 0: 8 lanes per batch split the k-loop, shfl_xor fp64 butterfly, then
// redundant-per-group Jacobi polar factor), then all 256 threads apply R,T.
__global__ __launch_bounds__(256) void k_apply(const float* __restrict__ srcf,
                                               const float* __restrict__ Zs,
                                               const float* __restrict__ Ss,
                                               float* __restrict__ out) {
    __shared__ float rt_s[BATCH][12];

    if (threadIdx.x < 64) {
        const int lane = threadIdx.x;
        const int b    = lane >> 3;
        const int sub  = lane & 7;

        const double inv_npi = 1.0 / (1.0 + 2e-8);        // Npi = 1+eps, /(Npi+eps)
        const double pi_c = (1.0 + 1e-8) / (double)N_PTS; // pi[b,k] constant

        double Mt[3] = {0, 0, 0}, Ms[3] = {0, 0, 0};
        double P[3][3] = {{0,0,0},{0,0,0},{0,0,0}};
        for (int kk = 0; kk < 8; ++kk) {
            int k  = sub * 8 + kk;
            int it = b * KCL + k;                 // set 0 (template)
            int is = (BATCH + b) * KCL + k;       // set 1 (source)
            double izt = inv_npi * drcp((double)Zs[it]);
            double izs = inv_npi * drcp((double)Zs[is]);
            double mt[3], ms[3];
            for (int d = 0; d < 3; ++d) {
                mt[d] = (double)Ss[it * 3 + d] * izt;
                ms[d] = (double)Ss[is * 3 + d] * izs;
                Mt[d] += mt[d];
                Ms[d] += ms[d];
            }
            for (int d = 0; d < 3; ++d)
                for (int e = 0; e < 3; ++e)
                    P[d][e] += mt[d] * ms[e];
        }
        // butterfly reduce across the 8 sub-lanes (masks 1,2,4 stay in-group)
        for (int m = 1; m <= 4; m <<= 1) {
            for (int d = 0; d < 3; ++d) {
                Mt[d] += __shfl_xor(Mt[d], m, 64);
                Ms[d] += __shfl_xor(Ms[d], m, 64);
            }
            for (int d = 0; d < 3; ++d)
                for (int e = 0; e < 3; ++e)
                    P[d][e] += __shfl_xor(P[d][e], m, 64);
        }

        // all 8 lanes of a batch-group now hold identical sums; proceed redundantly
        double cy[3], cx[3];
        for (int d = 0; d < 3; ++d) { cy[d] = pi_c * Mt[d]; cx[d] = pi_c * Ms[d]; }

        const double coef = 2.0 * pi_c - 64.0 * pi_c * pi_c;
        double A[3][3];
        for (int d = 0; d < 3; ++d)
            for (int e = 0; e < 3; ++e)
                A[d][e] = pi_c * (P[d][e] - coef * Mt[d] * Ms[e]);

        // G = A^T A
        double G[3][3];
        for (int i = 0; i < 3; ++i)
            for (int j = 0; j < 3; ++j) {
                double acc = 0;
                for (int d = 0; d < 3; ++d) acc += A[d][i] * A[d][j];
                G[i][j] = acc;
            }

        // Jacobi eigendecomposition of G
        double V[3][3] = {{1,0,0},{0,1,0},{0,0,1}};
        const int pairs[3][2] = {{0,1},{0,2},{1,2}};
        const double scale0 = fabs(G[0][0]) + fabs(G[1][1]) + fabs(G[2][2]) + 1e-300;
        for (int sweep = 0; sweep < 10; ++sweep) {
            double off = fabs(G[0][1]) + fabs(G[0][2]) + fabs(G[1][2]);
            if (off < 1e-28 * scale0) break;
            for (int pi_i = 0; pi_i < 3; ++pi_i) {
                int p = pairs[pi_i][0], q = pairs[pi_i][1];
                double apq = G[p][q];
                if (fabs(apq) < 1e-30 * scale0) continue;
                double tau = (G[q][q] - G[p][p]) * drcp(2.0 * apq);
                double t = ((tau >= 0) ? 1.0 : -1.0) * drcp(fabs(tau) + sqrt(1.0 + tau * tau));
                double c = drcp(sqrt(1.0 + t * t));
                double s = t * c;
                double gpp = G[p][p], gqq = G[q][q];
                G[p][p] = gpp - t * apq;
                G[q][q] = gqq + t * apq;
                G[p][q] = G[q][p] = 0.0;
                int r = 3 - p - q;
                double grp = G[r][p], grq = G[r][q];
                G[r][p] = G[p][r] = c * grp - s * grq;
                G[r][q] = G[q][r] = s * grp + c * grq;
                for (int rr = 0; rr < 3; ++rr) {
                    double vrp = V[rr][p], vrq = V[rr][q];
                    V[rr][p] = c * vrp - s * vrq;
                    V[rr][q] = s * vrp + c * vrq;
                }
            }
        }

        // M = V diag(1/sqrt(lam)) V^T ; R0 = A*M (polar factor = U@Vh)
        double invs[3];
        for (int i = 0; i < 3; ++i) {
            double lam = G[i][i];
            invs[i] = drcp(sqrt(lam > 1e-300 ? lam : 1e-300));
        }
        double M[3][3];
        for (int i = 0; i < 3; ++i)
            for (int j = 0; j < 3; ++j) {
                double acc = 0;
                for (int m2 = 0; m2 < 3; ++m2) acc += V[i][m2] * V[j][m2] * invs[m2];
                M[i][j] = acc;
            }
        double R0[3][3];
        for (int d = 0; d < 3; ++d)
            for (int e = 0; e < 3; ++e) {
                double acc = 0;
                for (int m2 = 0; m2 < 3; ++m2) acc += A[d][m2] * M[m2][e];
                R0[d][e] = acc;
            }

        // reference det-flip == flip 3rd column of R0
        double det = R0[0][0] * (R0[1][1] * R0[2][2] - R0[1][2] * R0[2][1])
                   - R0[0][1] * (R0[1][0] * R0[2][2] - R0[1][2] * R0[2][0])
                   + R0[0][2] * (R0[1][0] * R0[2][1] - R0[1][1] * R0[2][0]);
        double sg = (det >= 0.0) ? 1.0 : -1.0;
        R0[0][2] *= sg; R0[1][2] *= sg; R0[2][2] *= sg;

        double T[3];
        for (int d = 0; d < 3; ++d)
            T[d] = cy[d] - (R0[d][0] * cx[0] + R0[d][1] * cx[1] + R0[d][2] * cx[2]);

        if (sub == 0) {
            rt_s[b][0] = (float)R0[0][0]; rt_s[b][1] = (float)R0[0][1]; rt_s[b][2] = (float)R0[0][2];
            rt_s[b][3] = (float)R0[1][0]; rt_s[b][4] = (float)R0[1][1]; rt_s[b][5] = (float)R0[1][2];
            rt_s[b][6] = (float)R0[2][0]; rt_s[b][7] = (float)R0[2][1]; rt_s[b][8] = (float)R0[2][2];
            rt_s[b][9] = (float)T[0]; rt_s[b][10] = (float)T[1]; rt_s[b][11] = (float)T[2];
        }
    }
    __syncthreads();

    // apply: 512 blocks x 256 thr, 4 coalesced passes over B*N = 524288 points
    const int t = blockIdx.x * 256 + threadIdx.x;   // 0..131071
#pragma unroll
    for (int i = 0; i < 4; ++i) {
        int idx = t + i * 131072;
        int b = idx >> 16;
        int n = idx & (N_PTS - 1);
        const float* rt = rt_s[b];
        const float* base = srcf + (size_t)b * 3 * N_PTS;
        float x0 = base[n];
        float x1 = base[N_PTS + n];
        float x2 = base[2 * N_PTS + n];
        float y0 = fmaf(rt[0], x0, fmaf(rt[1], x1, fmaf(rt[2], x2, rt[9])));
        float y1 = fmaf(rt[3], x0, fmaf(rt[4], x1, fmaf(rt[5], x2, rt[10])));
        float y2 = fmaf(rt[6], x0, fmaf(rt[7], x1, fmaf(rt[8], x2, rt[11])));
        size_t o = (size_t)idx * 3;
        out[o + 0] = y0;
        out[o + 1] = y1;
        out[o + 2] = y2;
    }
}

extern "C" void kernel_launch(void* const* d_in, const int* in_sizes, int n_in,
                              void* d_out, int out_size, void* d_ws, size_t ws_size,
                              hipStream_t stream) {
    const float* tmpl = (const float*)d_in[0];   // (B,3,N) f32
    const float* srcf = (const float*)d_in[1];   // (B,3,N) f32
    const float* Wmat = (const float*)d_in[2];   // (3,K) f32
    float* out = (float*)d_out;                  // (B,N,3) f32

    // workspace (floats): [0,1024) Z | [1024,4096) S
    float* Zs = (float*)d_ws;
    float* Ss = (float*)d_ws + 1024;

    (void)hipMemsetAsync(d_ws, 0, 4096 * sizeof(float), stream);

    k_sum<<<512, 256, 0, stream>>>(tmpl, srcf, Wmat, Zs, Ss);
    k_apply<<<512, 256, 0, stream>>>(srcf, Zs, Ss, out);
}

// Round 5
// 92.945 us; speedup vs baseline: 1.7567x; 1.0834x over previous
//
#include <hip/hip_runtime.h>

#define N_PTS 65536
#define BATCH 8
#define KCL   64
#define CHUNK 1024
#define LOG2E 1.44269504088896340736f

typedef float f32x2 __attribute__((ext_vector_type(2)));
typedef float f32x4 __attribute__((ext_vector_type(4)));

// fp64 reciprocal: float rcp seed + 2 Newton iterations (quadratic: ~1e-7 -> 1e-14 -> <eps)
__device__ __forceinline__ double drcp(double x) {
    double r = (double)(1.0f / (float)x);
    r = r * (2.0 - x * r);
    r = r * (2.0 - x * r);
    return r;
}

__device__ __forceinline__ float hw_exp2(float x) {
    return __builtin_amdgcn_exp2f(x);
}

// K1: LDS-broadcast staging (scalar-load variant regressed: 2 waves/SIMD can't hide
// SMEM latency). 1024 blocks x 256 thr = 4096 waves = 4/SIMD. Block stages a
// 1024-point chunk of one (set,b) into LDS; each wave processes 256 points with
// lane = cluster k (per-lane accumulators ARE per-cluster). Inner math packed as
// float2 -> v_pk_fma_f32 (2 pts/inst): ~15 cyc/pt-wave vs 22 scalar.
// No max subtraction: logits bounded (|x.w| <~ 30; e^30*65536 ~ 7e17 << fp32 max).
__global__ __launch_bounds__(256) void k_sum(const float* __restrict__ tmpl,
                                             const float* __restrict__ srcf,
                                             const float* __restrict__ Wmat,
                                             float* __restrict__ Zs,
                                             float* __restrict__ Ss) {
    const int bx    = blockIdx.x;       // 0..1023
    const int set   = bx >> 9;          // 512 blocks per set
    const int b     = (bx >> 6) & 7;    // 64 blocks per (set,b)
    const int chunk = bx & 63;          // 1024-point chunk
    const float* feat = set ? srcf : tmpl;
    const int n0 = chunk * CHUNK;

    __shared__ float xs[3][CHUNK];
    __shared__ float red[4][KCL][4];

    const int tid = threadIdx.x;
    const float* base = feat + (size_t)b * 3 * N_PTS + n0;
    // stage 1024 points (3 planes) via coalesced float4
    for (int i = tid; i < 3 * (CHUNK / 4); i += 256) {
        int d = i / (CHUNK / 4);
        int p = i % (CHUNK / 4);
        float4 v = ((const float4*)(base + (size_t)d * N_PTS))[p];
        ((float4*)&xs[d][0])[p] = v;
    }
    __syncthreads();

    const int lane = tid & 63;   // lane <-> cluster k
    const int wv   = tid >> 6;
    // fold log2e so exp is one v_exp_f32
    const float w0 = Wmat[lane] * LOG2E;
    const float w1 = Wmat[KCL + lane] * LOG2E;
    const float w2 = Wmat[2 * KCL + lane] * LOG2E;
    const f32x2 w0v = {w0, w0}, w1v = {w1, w1}, w2v = {w2, w2};

    f32x2 z2 = {0.f, 0.f}, s02 = {0.f, 0.f}, s12 = {0.f, 0.f}, s22 = {0.f, 0.f};
    const int q0 = wv * (CHUNK / 16);   // 64 float4-groups per wave
#pragma unroll 2
    for (int q = q0; q < q0 + CHUNK / 16; ++q) {
        f32x4 a = ((const f32x4*)&xs[0][0])[q];   // broadcast ds_read_b128
        f32x4 c = ((const f32x4*)&xs[1][0])[q];
        f32x4 d = ((const f32x4*)&xs[2][0])[q];
        {
            f32x2 ax = a.xy, cx = c.xy, dx = d.xy;
            f32x2 l = __builtin_elementwise_fma(ax, w0v,
                        __builtin_elementwise_fma(cx, w1v, dx * w2v));
            f32x2 e = {hw_exp2(l.x), hw_exp2(l.y)};
            z2 += e;
            s02 = __builtin_elementwise_fma(e, ax, s02);
            s12 = __builtin_elementwise_fma(e, cx, s12);
            s22 = __builtin_elementwise_fma(e, dx, s22);
        }
        {
            f32x2 ax = a.zw, cx = c.zw, dx = d.zw;
            f32x2 l = __builtin_elementwise_fma(ax, w0v,
                        __builtin_elementwise_fma(cx, w1v, dx * w2v));
            f32x2 e = {hw_exp2(l.x), hw_exp2(l.y)};
            z2 += e;
            s02 = __builtin_elementwise_fma(e, ax, s02);
            s12 = __builtin_elementwise_fma(e, cx, s12);
            s22 = __builtin_elementwise_fma(e, dx, s22);
        }
    }

    red[wv][lane][0] = z2.x + z2.y;
    red[wv][lane][1] = s02.x + s02.y;
    red[wv][lane][2] = s12.x + s12.y;
    red[wv][lane][3] = s22.x + s22.y;
    __syncthreads();
    if (tid < KCL) {
        float rz  = red[0][tid][0] + red[1][tid][0] + red[2][tid][0] + red[3][tid][0];
        float rs0 = red[0][tid][1] + red[1][tid][1] + red[2][tid][1] + red[3][tid][1];
        float rs1 = red[0][tid][2] + red[1][tid][2] + red[2][tid][2] + red[3][tid][2];
        float rs2 = red[0][tid][3] + red[1][tid][3] + red[2][tid][3] + red[3][tid][3];
        int idx = (set * BATCH + b) * KCL + tid;
        atomicAdd(&Zs[idx], rz);
        atomicAdd(&Ss[idx * 3 + 0], rs0);
        atomicAdd(&Ss[idx * 3 + 1], rs1);
        atomicAdd(&Ss[idx * 3 + 2], rs2);
    }
}

// K2 (fused): every block redundantly solves the 8 per-batch transforms into LDS
// (wave 0: 8 lanes per batch split the k-loop, shfl_xor fp64 butterfly, then
// redundant-per-group Jacobi polar factor), then all 256 threads apply R,T.
__global__ __launch_bounds__(256) void k_apply(const float* __restrict__ srcf,
                                               const float* __restrict__ Zs,
                                               const float* __restrict__ Ss,
                                               float* __restrict__ out) {
    __shared__ float rt_s[BATCH][12];

    if (threadIdx.x < 64) {
        const int lane = threadIdx.x;
        const int b    = lane >> 3;
        const int sub  = lane & 7;

        const double inv_npi = 1.0 / (1.0 + 2e-8);        // Npi = 1+eps, /(Npi+eps)
        const double pi_c = (1.0 + 1e-8) / (double)N_PTS; // pi[b,k] constant

        double Mt[3] = {0, 0, 0}, Ms[3] = {0, 0, 0};
        double P[3][3] = {{0,0,0},{0,0,0},{0,0,0}};
        for (int kk = 0; kk < 8; ++kk) {
            int k  = sub * 8 + kk;
            int it = b * KCL + k;                 // set 0 (template)
            int is = (BATCH + b) * KCL + k;       // set 1 (source)
            double izt = inv_npi * drcp((double)Zs[it]);
            double izs = inv_npi * drcp((double)Zs[is]);
            double mt[3], ms[3];
            for (int d = 0; d < 3; ++d) {
                mt[d] = (double)Ss[it * 3 + d] * izt;
                ms[d] = (double)Ss[is * 3 + d] * izs;
                Mt[d] += mt[d];
                Ms[d] += ms[d];
            }
            for (int d = 0; d < 3; ++d)
                for (int e = 0; e < 3; ++e)
                    P[d][e] += mt[d] * ms[e];
        }
        // butterfly reduce across the 8 sub-lanes (masks 1,2,4 stay in-group)
        for (int m = 1; m <= 4; m <<= 1) {
            for (int d = 0; d < 3; ++d) {
                Mt[d] += __shfl_xor(Mt[d], m, 64);
                Ms[d] += __shfl_xor(Ms[d], m, 64);
            }
            for (int d = 0; d < 3; ++d)
                for (int e = 0; e < 3; ++e)
                    P[d][e] += __shfl_xor(P[d][e], m, 64);
        }

        // all 8 lanes of a batch-group now hold identical sums; proceed redundantly
        double cy[3], cx[3];
        for (int d = 0; d < 3; ++d) { cy[d] = pi_c * Mt[d]; cx[d] = pi_c * Ms[d]; }

        const double coef = 2.0 * pi_c - 64.0 * pi_c * pi_c;
        double A[3][3];
        for (int d = 0; d < 3; ++d)
            for (int e = 0; e < 3; ++e)
                A[d][e] = pi_c * (P[d][e] - coef * Mt[d] * Ms[e]);

        // G = A^T A
        double G[3][3];
        for (int i = 0; i < 3; ++i)
            for (int j = 0; j < 3; ++j) {
                double acc = 0;
                for (int d = 0; d < 3; ++d) acc += A[d][i] * A[d][j];
                G[i][j] = acc;
            }

        // Jacobi eigendecomposition of G
        double V[3][3] = {{1,0,0},{0,1,0},{0,0,1}};
        const int pairs[3][2] = {{0,1},{0,2},{1,2}};
        const double scale0 = fabs(G[0][0]) + fabs(G[1][1]) + fabs(G[2][2]) + 1e-300;
        for (int sweep = 0; sweep < 10; ++sweep) {
            double off = fabs(G[0][1]) + fabs(G[0][2]) + fabs(G[1][2]);
            if (off < 1e-28 * scale0) break;
            for (int pi_i = 0; pi_i < 3; ++pi_i) {
                int p = pairs[pi_i][0], q = pairs[pi_i][1];
                double apq = G[p][q];
                if (fabs(apq) < 1e-30 * scale0) continue;
                double tau = (G[q][q] - G[p][p]) * drcp(2.0 * apq);
                double t = ((tau >= 0) ? 1.0 : -1.0) * drcp(fabs(tau) + sqrt(1.0 + tau * tau));
                double c = drcp(sqrt(1.0 + t * t));
                double s = t * c;
                double gpp = G[p][p], gqq = G[q][q];
                G[p][p] = gpp - t * apq;
                G[q][q] = gqq + t * apq;
                G[p][q] = G[q][p] = 0.0;
                int r = 3 - p - q;
                double grp = G[r][p], grq = G[r][q];
                G[r][p] = G[p][r] = c * grp - s * grq;
                G[r][q] = G[q][r] = s * grp + c * grq;
                for (int rr = 0; rr < 3; ++rr) {
                    double vrp = V[rr][p], vrq = V[rr][q];
                    V[rr][p] = c * vrp - s * vrq;
                    V[rr][q] = s * vrp + c * vrq;
                }
            }
        }

        // M = V diag(1/sqrt(lam)) V^T ; R0 = A*M (polar factor = U@Vh)
        double invs[3];
        for (int i = 0; i < 3; ++i) {
            double lam = G[i][i];
            invs[i] = drcp(sqrt(lam > 1e-300 ? lam : 1e-300));
        }
        double M[3][3];
        for (int i = 0; i < 3; ++i)
            for (int j = 0; j < 3; ++j) {
                double acc = 0;
                for (int m2 = 0; m2 < 3; ++m2) acc += V[i][m2] * V[j][m2] * invs[m2];
                M[i][j] = acc;
            }
        double R0[3][3];
        for (int d = 0; d < 3; ++d)
            for (int e = 0; e < 3; ++e) {
                double acc = 0;
                for (int m2 = 0; m2 < 3; ++m2) acc += A[d][m2] * M[m2][e];
                R0[d][e] = acc;
            }

        // reference det-flip == flip 3rd column of R0
        double det = R0[0][0] * (R0[1][1] * R0[2][2] - R0[1][2] * R0[2][1])
                   - R0[0][1] * (R0[1][0] * R0[2][2] - R0[1][2] * R0[2][0])
                   + R0[0][2] * (R0[1][0] * R0[2][1] - R0[1][1] * R0[2][0]);
        double sg = (det >= 0.0) ? 1.0 : -1.0;
        R0[0][2] *= sg; R0[1][2] *= sg; R0[2][2] *= sg;

        double T[3];
        for (int d = 0; d < 3; ++d)
            T[d] = cy[d] - (R0[d][0] * cx[0] + R0[d][1] * cx[1] + R0[d][2] * cx[2]);

        if (sub == 0) {
            rt_s[b][0] = (float)R0[0][0]; rt_s[b][1] = (float)R0[0][1]; rt_s[b][2] = (float)R0[0][2];
            rt_s[b][3] = (float)R0[1][0]; rt_s[b][4] = (float)R0[1][1]; rt_s[b][5] = (float)R0[1][2];
            rt_s[b][6] = (float)R0[2][0]; rt_s[b][7] = (float)R0[2][1]; rt_s[b][8] = (float)R0[2][2];
            rt_s[b][9] = (float)T[0]; rt_s[b][10] = (float)T[1]; rt_s[b][11] = (float)T[2];
        }
    }
    __syncthreads();

    // apply: 512 blocks x 256 thr, 4 coalesced passes over B*N = 524288 points
    const int t = blockIdx.x * 256 + threadIdx.x;   // 0..131071
#pragma unroll
    for (int i = 0; i < 4; ++i) {
        int idx = t + i * 131072;
        int b = idx >> 16;
        int n = idx & (N_PTS - 1);
        const float* rt = rt_s[b];
        const float* base = srcf + (size_t)b * 3 * N_PTS;
        float x0 = base[n];
        float x1 = base[N_PTS + n];
        float x2 = base[2 * N_PTS + n];
        float y0 = fmaf(rt[0], x0, fmaf(rt[1], x1, fmaf(rt[2], x2, rt[9])));
        float y1 = fmaf(rt[3], x0, fmaf(rt[4], x1, fmaf(rt[5], x2, rt[10])));
        float y2 = fmaf(rt[6], x0, fmaf(rt[7], x1, fmaf(rt[8], x2, rt[11])));
        size_t o = (size_t)idx * 3;
        out[o + 0] = y0;
        out[o + 1] = y1;
        out[o + 2] = y2;
    }
}

extern "C" void kernel_launch(void* const* d_in, const int* in_sizes, int n_in,
                              void* d_out, int out_size, void* d_ws, size_t ws_size,
                              hipStream_t stream) {
    const float* tmpl = (const float*)d_in[0];   // (B,3,N) f32
    const float* srcf = (const float*)d_in[1];   // (B,3,N) f32
    const float* Wmat = (const float*)d_in[2];   // (3,K) f32
    float* out = (float*)d_out;                  // (B,N,3) f32

    // workspace (floats): [0,1024) Z | [1024,4096) S
    float* Zs = (float*)d_ws;
    float* Ss = (float*)d_ws + 1024;

    (void)hipMemsetAsync(d_ws, 0, 4096 * sizeof(float), stream);

    k_sum<<<1024, 256, 0, stream>>>(tmpl, srcf, Wmat, Zs, Ss);
    k_apply<<<512, 256, 0, stream>>>(srcf, Zs, Ss, out);
}